// Round 4
// baseline (72.839 us; speedup 1.0000x reference)
//
#include <hip/hip_runtime.h>
#include <math.h>

// Problem constants (fixed by reference): B=256 batches, N=M=256 points, D=4.
#define BB 256
#define NN 256
#define MM 256

#define POISON  1.0e18f   // invalid-point coordinate: dist^2 ~ 4e36, finite, loses every min
#define MINSENT 3.0e38f

// One block per batch, 1024 threads.
//   staging : threads 0..511 (256 target + 256 reco), poisoned points + |p|^2 + masks in LDS
//   passes  : threads 0..511 row-mins (X->R), 512..1023 col-mins (R->X);
//             each thread owns 8 rows x one 16-wide chunk of the other set.
//             dist^2 via |x|^2 + |y|^2 - 2 x.y : 6 VALU/pair (4 fma + add + min)
//   epilogue: threads 0..511 combine chunk-mins (256 rows + 256 cols in parallel),
//             per-wave shuffle reduce, thread 0 atomicAdds the batch means into out.
__global__ __launch_bounds__(1024) void chamfer_batch_kernel(
    const float* __restrict__ target,   // [B, N, 4]
    const float* __restrict__ reco,     // [B, M, 4]
    const int*   __restrict__ in_pid,   // [B, N]
    const int*   __restrict__ out_pid,  // [B, M]
    float* __restrict__ out)            // [2] accumulated means
{
    const int b = blockIdx.x;
    const int t = threadIdx.x;   // 0..1023

    __shared__ float4 sT[NN];                    // masked target points, 4 KB
    __shared__ float4 sR[MM];                    // masked reco points, 4 KB
    __shared__ __align__(16) float sTh[NN];      // |sT|^2 (poisoned), 1 KB
    __shared__ __align__(16) float sRh[MM];      // |sR|^2 (poisoned), 1 KB
    __shared__ float sRn[MM];                    // RAW reco norms (for zero-pid term), 1 KB
    __shared__ int   sMx[NN], sMy[MM];           // masks, 2 KB
    __shared__ float pmin1[16][NN];              // row-min partials per 16-chunk, 16 KB
    __shared__ float pmin2[16][MM];              // col-min partials per 16-chunk, 16 KB
    __shared__ int   cnt[8];                     // per-wave popcounts (w0-3: nx, w4-7: ny)
    __shared__ float wred[8][2];                 // per-wave reduction slots

    // ---- stage batch b into LDS: threads 0..255 target, 256..511 reco ----
    if (t < 512) {
        const bool isT = (t < 256);
        const int  i   = isT ? t : (t - 256);
        const float4* src = isT ? (const float4*)(target + (size_t)b * NN * 4)
                                : (const float4*)(reco   + (size_t)b * MM * 4);
        const int*    pid = isT ? (in_pid + b * NN) : (out_pid + b * MM);
        float4 p = src[i];
        const int m = (pid[i] != 0);
        const float rawsq = fmaf(p.x, p.x, fmaf(p.y, p.y, fmaf(p.z, p.z, p.w * p.w)));
        float4 pp = m ? p : make_float4(POISON, POISON, POISON, POISON);
        const float ppsq = m ? rawsq : (4.0f * POISON * POISON);
        if (isT) {
            sT[i]  = pp;
            sTh[i] = ppsq;
            sMx[i] = m;
        } else {
            sR[i]  = pp;
            sRh[i] = ppsq;
            sMy[i] = m;
            sRn[i] = sqrtf(rawsq);
        }
        const unsigned long long bal = __ballot(m);   // waves 0..7 fully active here
        if ((t & 63) == 0) cnt[t >> 6] = (int)__popcll(bal);
    }
    __syncthreads();

    // ---- concurrent min passes, 8-way register tiling, 6 VALU per pair ----
    {
        const bool pass1 = (t < 512);
        const int  u = pass1 ? t : (t - 512);
        const int  c = u >> 5;        // 0..15 : 16-wide chunk of the scanned set
        const int  g = u & 31;        // rows g, g+32, ..., g+224
        const float4* own    = pass1 ? sT : sR;
        const float4* other  = pass1 ? sR : sT;
        const float4* otherH = pass1 ? (const float4*)sRh : (const float4*)sTh;
        float (*pout)[256]   = pass1 ? pmin1 : pmin2;

        float4 n2[8];   // -2 * own point
        float  hx[8];   // |own point|^2
        #pragma unroll
        for (int k = 0; k < 8; ++k) {
            const float4 p = own[g + (k << 5)];
            n2[k] = make_float4(-2.f * p.x, -2.f * p.y, -2.f * p.z, -2.f * p.w);
            hx[k] = fmaf(p.x, p.x, fmaf(p.y, p.y, fmaf(p.z, p.z, p.w * p.w)));
        }
        float mn[8];
        #pragma unroll
        for (int k = 0; k < 8; ++k) mn[k] = MINSENT;

        const int base = c << 4;
        #pragma unroll
        for (int j = 0; j < 4; ++j) {
            const float4 hy4 = otherH[(c << 2) + j];   // |y|^2 for 4 scanned points
            #pragma unroll
            for (int i = 0; i < 4; ++i) {
                const float4 r  = other[base + (j << 2) + i];
                const float  hy = (i == 0) ? hy4.x : (i == 1) ? hy4.y : (i == 2) ? hy4.z : hy4.w;
                #pragma unroll
                for (int k = 0; k < 8; ++k) {
                    float acc = fmaf(n2[k].x, r.x, hx[k]);
                    acc = fmaf(n2[k].y, r.y, acc);
                    acc = fmaf(n2[k].z, r.z, acc);
                    acc = fmaf(n2[k].w, r.w, acc);
                    mn[k] = fminf(mn[k], acc + hy);    // = |x|^2+|y|^2-2x.y
                }
            }
        }
        #pragma unroll
        for (int k = 0; k < 8; ++k) pout[c][g + (k << 5)] = mn[k];
    }
    __syncthreads();

    // ---- epilogue: 512 threads, one row/col each ----
    if (t < 512) {
        const bool rows = (t < 256);
        const int  i = rows ? t : (t - 256);
        float (*pm)[256] = rows ? pmin1 : pmin2;
        float m = pm[0][i];
        #pragma unroll
        for (int c = 1; c < 16; ++c) m = fminf(m, pm[c][i]);
        m = fmaxf(m, 0.0f);                          // guard fma-rounding negatives
        const int msk = rows ? sMx[i] : sMy[i];
        float va, vb;
        if (rows) {
            va = msk ? sqrtf(m) : 0.f;               // -> sum_xy
            vb = msk ? sqrtf(sTh[i]) : 0.f;          // -> sum ||x|| over nonzero pid
        } else {
            va = msk ? sqrtf(m) : 0.f;               // -> sum_yx
            vb = msk ? 0.f : sRn[i];                 // -> sum ||y|| over zero pid
        }
        #pragma unroll
        for (int off = 32; off > 0; off >>= 1) {
            va += __shfl_down(va, off, 64);
            vb += __shfl_down(vb, off, 64);
        }
        if ((t & 63) == 0) {
            wred[t >> 6][0] = va;
            wred[t >> 6][1] = vb;
        }
    }
    __syncthreads();

    if (t == 0) {
        float s_xy = 0.f, s_nx = 0.f, s_yx = 0.f, s_ny0 = 0.f;
        int nx = 0, ny = 0;
        #pragma unroll
        for (int w = 0; w < 4; ++w) {
            s_xy  += wred[w][0];
            s_nx  += wred[w][1];
            s_yx  += wred[w + 4][0];
            s_ny0 += wred[w + 4][1];
            nx    += cnt[w];
            ny    += cnt[w + 4];
        }
        const float n_in  = (float)max(1, nx);
        const float n_out = (float)max(1, ny);
        const float normal = 0.5f * (s_xy / n_out + s_yx / n_in);
        const float eucl_nz = (ny == 0) ? (s_nx / n_in)
                                        : ((nx == 0) ? 0.0f : normal);
        const float n_zero = (float)max(1, MM - ny);
        const float eucl_z = s_ny0 / n_zero;
        atomicAdd(&out[0], eucl_nz * (1.0f / BB));
        atomicAdd(&out[1], eucl_z  * (1.0f / BB));
    }
}

extern "C" void kernel_launch(void* const* d_in, const int* in_sizes, int n_in,
                              void* d_out, int out_size, void* d_ws, size_t ws_size,
                              hipStream_t stream) {
    const float* target  = (const float*)d_in[0];
    const float* reco    = (const float*)d_in[1];
    const int*   in_pid  = (const int*)d_in[2];
    const int*   out_pid = (const int*)d_in[3];
    float* out = (float*)d_out;

    // d_out is poisoned to 0xAA before every timed launch; we accumulate via
    // atomicAdd, so zero the 8 bytes first (async memset is graph-capture safe).
    hipMemsetAsync(out, 0, (size_t)out_size * sizeof(float), stream);

    chamfer_batch_kernel<<<dim3(BB), dim3(1024), 0, stream>>>(
        target, reco, in_pid, out_pid, out);
}

// Round 5
// 66.233 us; speedup vs baseline: 1.0997x; 1.0997x over previous
//
#include <hip/hip_runtime.h>
#include <math.h>

// Problem constants (fixed by reference): B=256 batches, N=M=256 points, D=4.
#define BB 256
#define NN 256
#define MM 256

#define POISON  1.0e18f   // invalid-point coordinate: dist^2 ~ 4e36, finite, loses every min
#define MINSENT 3.0e38f

typedef float f2 __attribute__((ext_vector_type(2)));
__device__ __forceinline__ f2 splat2(float v) { f2 r; r.x = v; r.y = v; return r; }

// Kernel 1: one block per batch, 1024 threads.
//   staging : threads 0..511 stage points into AoS (own-side) + SoA planes (scan-side),
//             poisoned, plus |p|^2 plane, masks, raw reco norms.
//   passes  : threads 0..511 row-mins (X->R), 512..1023 col-mins (R->X).
//             Each thread: 4 own rows x one 32-wide scanned chunk. dist^2 via
//             |x|^2+|y|^2-2x.y computed 2-points-at-a-time with packed fp32
//             (v_pk_fma_f32): ~3.5 VALU/pair. c = u>>6 is wave-uniform so all
//             scanned SoA reads are single-address broadcasts (conflict-free).
//   epilogue: threads 0..511 combine 8 chunk-mins per row/col, wave-reduce,
//             thread 0 plain-stores the batch pair to ws[b]. No atomics.
__global__ __launch_bounds__(1024) void chamfer_batch_kernel(
    const float* __restrict__ target,   // [B, N, 4]
    const float* __restrict__ reco,     // [B, M, 4]
    const int*   __restrict__ in_pid,   // [B, N]
    const int*   __restrict__ out_pid,  // [B, M]
    float2* __restrict__ ws)            // [B] per-batch (eucl_nonzero, eucl_zero)
{
    const int b = blockIdx.x;
    const int t = threadIdx.x;   // 0..1023

    __shared__ float4 sT[NN], sR[MM];                 // AoS poisoned points, 8 KB
    __shared__ __align__(16) float sTx[NN], sTy[NN], sTz[NN], sTw[NN], sTh[NN]; // SoA, 5 KB
    __shared__ __align__(16) float sRx[MM], sRy[MM], sRz[MM], sRw[MM], sRh[MM]; // SoA, 5 KB
    __shared__ float sRn[MM];                         // RAW reco norms, 1 KB
    __shared__ int   sMx[NN], sMy[MM];                // masks, 2 KB
    __shared__ float pmin1[8][NN], pmin2[8][MM];      // chunk-min partials, 16 KB
    __shared__ int   cnt[8];                          // per-wave popcounts
    __shared__ float wred[8][2];                      // wave-reduction slots

    // ---- stage: threads 0..255 target, 256..511 reco ----
    if (t < 512) {
        const bool isT = (t < 256);
        const int  i   = isT ? t : (t - 256);
        const float4* src = isT ? (const float4*)(target + (size_t)b * NN * 4)
                                : (const float4*)(reco   + (size_t)b * MM * 4);
        const int*    pid = isT ? (in_pid + b * NN) : (out_pid + b * MM);
        float4 p = src[i];
        const int m = (pid[i] != 0);
        const float rawsq = fmaf(p.x, p.x, fmaf(p.y, p.y, fmaf(p.z, p.z, p.w * p.w)));
        float4 pp = m ? p : make_float4(POISON, POISON, POISON, POISON);
        const float ppsq = m ? rawsq : (4.0f * POISON * POISON);
        if (isT) {
            sT[i] = pp;
            sTx[i] = pp.x; sTy[i] = pp.y; sTz[i] = pp.z; sTw[i] = pp.w; sTh[i] = ppsq;
            sMx[i] = m;
        } else {
            sR[i] = pp;
            sRx[i] = pp.x; sRy[i] = pp.y; sRz[i] = pp.z; sRw[i] = pp.w; sRh[i] = ppsq;
            sMy[i] = m;
            sRn[i] = sqrtf(rawsq);
        }
        const unsigned long long bal = __ballot(m);   // waves 0..7 fully active here
        if ((t & 63) == 0) cnt[t >> 6] = (int)__popcll(bal);
    }
    __syncthreads();

    // ---- packed-math min passes ----
    {
        const bool pass1 = (t < 512);
        const int  u = pass1 ? t : (t - 512);
        const int  c = u >> 6;          // 0..7, wave-uniform
        const int  g = u & 63;          // own rows g, g+64, g+128, g+192
        const float4* own  = pass1 ? sT  : sR;
        const float*  ownH = pass1 ? sTh : sRh;
        const float*  ox   = pass1 ? sRx : sTx;
        const float*  oy   = pass1 ? sRy : sTy;
        const float*  oz   = pass1 ? sRz : sTz;
        const float*  owp  = pass1 ? sRw : sTw;
        const float*  oh   = pass1 ? sRh : sTh;
        float (*pout)[256] = pass1 ? pmin1 : pmin2;

        f2 n2x[4], n2y[4], n2z[4], n2w[4], hx[4], mn[4];
        #pragma unroll
        for (int k = 0; k < 4; ++k) {
            const float4 p = own[g + (k << 6)];
            n2x[k] = splat2(-2.f * p.x);
            n2y[k] = splat2(-2.f * p.y);
            n2z[k] = splat2(-2.f * p.z);
            n2w[k] = splat2(-2.f * p.w);
            hx[k]  = splat2(ownH[g + (k << 6)]);
            mn[k]  = splat2(MINSENT);
        }

        const int base = c << 5;        // 32-wide scanned chunk
        #pragma unroll
        for (int q = 0; q < 8; ++q) {   // 4 scanned points per iteration
            const int o = base + (q << 2);
            const float4 rx4 = *(const float4*)&ox[o];
            const float4 ry4 = *(const float4*)&oy[o];
            const float4 rz4 = *(const float4*)&oz[o];
            const float4 rw4 = *(const float4*)&owp[o];
            const float4 rh4 = *(const float4*)&oh[o];
            f2 rx0, rx1, ry0, ry1, rz0, rz1, rw0, rw1, rh0, rh1;
            rx0.x = rx4.x; rx0.y = rx4.y;  rx1.x = rx4.z; rx1.y = rx4.w;
            ry0.x = ry4.x; ry0.y = ry4.y;  ry1.x = ry4.z; ry1.y = ry4.w;
            rz0.x = rz4.x; rz0.y = rz4.y;  rz1.x = rz4.z; rz1.y = rz4.w;
            rw0.x = rw4.x; rw0.y = rw4.y;  rw1.x = rw4.z; rw1.y = rw4.w;
            rh0.x = rh4.x; rh0.y = rh4.y;  rh1.x = rh4.z; rh1.y = rh4.w;
            #pragma unroll
            for (int k = 0; k < 4; ++k) {
                f2 a0 = __builtin_elementwise_fma(n2x[k], rx0, hx[k]);
                a0 = __builtin_elementwise_fma(n2y[k], ry0, a0);
                a0 = __builtin_elementwise_fma(n2z[k], rz0, a0);
                a0 = __builtin_elementwise_fma(n2w[k], rw0, a0);
                a0 = a0 + rh0;                       // = |x|^2+|y|^2-2x.y (2 points)
                mn[k] = __builtin_elementwise_min(mn[k], a0);
                f2 a1 = __builtin_elementwise_fma(n2x[k], rx1, hx[k]);
                a1 = __builtin_elementwise_fma(n2y[k], ry1, a1);
                a1 = __builtin_elementwise_fma(n2z[k], rz1, a1);
                a1 = __builtin_elementwise_fma(n2w[k], rw1, a1);
                a1 = a1 + rh1;
                mn[k] = __builtin_elementwise_min(mn[k], a1);
            }
        }
        #pragma unroll
        for (int k = 0; k < 4; ++k)
            pout[c][g + (k << 6)] = fminf(mn[k].x, mn[k].y);
    }
    __syncthreads();

    // ---- epilogue: 512 threads, one row/col each ----
    if (t < 512) {
        const bool rows = (t < 256);
        const int  i = rows ? t : (t - 256);
        float (*pm)[256] = rows ? pmin1 : pmin2;
        float m = pm[0][i];
        #pragma unroll
        for (int c2 = 1; c2 < 8; ++c2) m = fminf(m, pm[c2][i]);
        m = fmaxf(m, 0.0f);                          // guard fma-rounding negatives
        const int msk = rows ? sMx[i] : sMy[i];
        float va, vb;
        if (rows) {
            va = msk ? sqrtf(m) : 0.f;               // -> sum_xy
            vb = msk ? sqrtf(sTh[i]) : 0.f;          // -> sum ||x|| over nonzero pid
        } else {
            va = msk ? sqrtf(m) : 0.f;               // -> sum_yx
            vb = msk ? 0.f : sRn[i];                 // -> sum ||y|| over zero pid
        }
        #pragma unroll
        for (int off = 32; off > 0; off >>= 1) {
            va += __shfl_down(va, off, 64);
            vb += __shfl_down(vb, off, 64);
        }
        if ((t & 63) == 0) {
            wred[t >> 6][0] = va;
            wred[t >> 6][1] = vb;
        }
    }
    __syncthreads();

    if (t == 0) {
        float s_xy = 0.f, s_nx = 0.f, s_yx = 0.f, s_ny0 = 0.f;
        int nx = 0, ny = 0;
        #pragma unroll
        for (int w = 0; w < 4; ++w) {
            s_xy  += wred[w][0];
            s_nx  += wred[w][1];
            s_yx  += wred[w + 4][0];
            s_ny0 += wred[w + 4][1];
            nx    += cnt[w];
            ny    += cnt[w + 4];
        }
        const float n_in  = (float)max(1, nx);
        const float n_out = (float)max(1, ny);
        const float normal = 0.5f * (s_xy / n_out + s_yx / n_in);
        const float eucl_nz = (ny == 0) ? (s_nx / n_in)
                                        : ((nx == 0) ? 0.0f : normal);
        const float n_zero = (float)max(1, MM - ny);
        const float eucl_z = s_ny0 / n_zero;
        ws[b] = make_float2(eucl_nz, eucl_z);   // plain store, no atomics
    }
}

// Kernel 2: one wave reduces 256 per-batch pairs; plain stores, no LDS/barrier.
__global__ __launch_bounds__(64) void chamfer_final_kernel(
    const float2* __restrict__ ws, float* __restrict__ out)
{
    const int t = threadIdx.x;   // 0..63
    float a = 0.f, z = 0.f;
    #pragma unroll
    for (int k = 0; k < 4; ++k) {
        const float2 v = ws[t + (k << 6)];
        a += v.x;
        z += v.y;
    }
    #pragma unroll
    for (int off = 32; off > 0; off >>= 1) {
        a += __shfl_down(a, off, 64);
        z += __shfl_down(z, off, 64);
    }
    if (t == 0) {
        out[0] = a * (1.0f / BB);
        out[1] = z * (1.0f / BB);
    }
}

extern "C" void kernel_launch(void* const* d_in, const int* in_sizes, int n_in,
                              void* d_out, int out_size, void* d_ws, size_t ws_size,
                              hipStream_t stream) {
    const float* target  = (const float*)d_in[0];
    const float* reco    = (const float*)d_in[1];
    const int*   in_pid  = (const int*)d_in[2];
    const int*   out_pid = (const int*)d_in[3];
    float* out = (float*)d_out;
    float2* ws = (float2*)d_ws;

    chamfer_batch_kernel<<<dim3(BB), dim3(1024), 0, stream>>>(
        target, reco, in_pid, out_pid, ws);
    chamfer_final_kernel<<<dim3(1), dim3(64), 0, stream>>>(ws, out);
}